// Round 13
// baseline (34.643 us; speedup 1.0000x reference)
//
#include <hip/hip_runtime.h>
#include <hip/hip_bf16.h>

typedef __attribute__((ext_vector_type(8))) short short8;
typedef __attribute__((ext_vector_type(4))) short short4v;
typedef __attribute__((ext_vector_type(4))) float floatx4;
typedef __attribute__((ext_vector_type(4))) int intx4;
typedef unsigned int u32;
typedef unsigned short u16;

#define NB 1024
#define ND 16
#define NM 4
#define NR 4096
#define NC 64
#define EPSF 1e-9f
#define PADK 4112  // afrag row stride: 8-bank shift between M-rows

__device__ inline u16 f2bf(float f) {
    u32 u;
    __builtin_memcpy(&u, &f, 4);
    u32 lsb = (u >> 16) & 1;
    u += 0x7fffu + lsb;   // round-to-nearest-even
    return (u16)(u >> 16);
}
__device__ inline float bf2f(u16 v) {
    u32 u = ((u32)v) << 16;
    float f;
    __builtin_memcpy(&f, &u, 4);
    return f;
}

// ---- Kernel 1: blocks 0..255 cons-reduce -> s_consT[c][r] bf16; 256..271 pack rules ----
__global__ __launch_bounds__(256) void k_prep(const float* __restrict__ cons,
                                              const int* __restrict__ rules,
                                              u16* __restrict__ s_consT,
                                              u32* __restrict__ packed) {
    __shared__ u16 tile[16][68];
    int bid = blockIdx.x;
    int tid = threadIdx.x;
    if (bid >= 256) {
        int r = (bid - 256) * 256 + tid;
        const int* q = rules + (size_t)r * ND;
        u32 pk = 0;
#pragma unroll
        for (int i = 0; i < 4; ++i) {
            intx4 v = *(const intx4*)(q + i * 4);
#pragma unroll
            for (int e = 0; e < 4; ++e) pk |= ((u32)(v[e] & 3)) << (2 * (i * 4 + e));
        }
        packed[r] = pk;
        return;
    }
    int rbase = bid * 16;
    int c = tid & 63;
    int rr = tid >> 6;
#pragma unroll
    for (int it = 0; it < 4; ++it, rr += 4) {
        const float* p = cons + (size_t)(rbase + rr) * (ND + 1) * NC + c;
        float s = 0.f;
#pragma unroll
        for (int j = 0; j < ND + 1; ++j) s += p[j * NC];
        tile[rr][c] = f2bf(s);
    }
    __syncthreads();
    int cc = tid >> 2;
    int r0 = (tid & 3) * 4;
    short4v v;
#pragma unroll
    for (int e = 0; e < 4; ++e) v[e] = (short)tile[r0 + e][cc];
    *(short4v*)(s_consT + (size_t)cc * NR + rbase + r0) = v;
}

// ---- Kernel 2 (fused): block = 4 batch rows. fs per wave -> nfs + LDS A; gemm; out ----
__global__ __launch_bounds__(256) void k_fused(const float* __restrict__ x,
                                               const float* __restrict__ centers,
                                               const float* __restrict__ widths,
                                               const u32* __restrict__ packed,
                                               const u16* __restrict__ s_consT,
                                               float* __restrict__ out_nfs,
                                               float* __restrict__ out_xe,
                                               float* __restrict__ out_rule) {
    __shared__ __align__(16) u16 afrag[4][PADK];
    __shared__ float gtab[4][1024];
    __shared__ float mftab[4][64];
    __shared__ float xv[4][16];
    __shared__ float rs[4];
    int b0 = blockIdx.x * 4;
    int tid = threadIdx.x;
    int w = tid >> 6, lane = tid & 63;
    int b = b0 + w;

    // ---- per-wave fs for row b ----
    if (lane < 16) {
        float raw = x[b * 16 + lane];
        xv[w][lane] = raw;
        out_xe[(size_t)b * 17 + lane] = raw;
    }
    if (lane == 16) out_xe[(size_t)b * 17 + 16] = 1.0f;
    // membership: lane = d*4+m
    {
        float diff = xv[w][lane >> 2] - centers[lane];
        float wd = widths[lane];
        mftab[w][lane] = __expf(-diff * diff / (2.f * wd * wd)) + EPSF;
    }
    // group product tables: 4 groups x 256
#pragma unroll
    for (int it = 0; it < 16; ++it) {
        int idx = it * 64 + lane;
        int g = idx >> 8, i = idx & 255;
        const float* mf = &mftab[w][g * 16];
        gtab[w][idx] = mf[i & 3] * mf[4 + ((i >> 2) & 3)] *
                       mf[8 + ((i >> 4) & 3)] * mf[12 + ((i >> 6) & 3)];
    }
    // firing strengths: 64 rules per lane
    const float* gt = gtab[w];
    float lsum = 0.f;
#pragma unroll 8
    for (int it = 0; it < 64; ++it) {
        int r = it * 64 + lane;
        u32 pk = packed[r];
        float f = gt[pk & 255] * gt[256 + ((pk >> 8) & 255)] *
                  gt[512 + ((pk >> 16) & 255)] * gt[768 + (pk >> 24)];
        afrag[w][r] = f2bf(f);
        lsum += f;
    }
#pragma unroll
    for (int off = 32; off; off >>= 1) lsum += __shfl_xor(lsum, off, 64);
    float inv = 1.f / (lsum + EPSF);
    if (lane == 0) {
        float s = 1.f;
#pragma unroll
        for (int i = 0; i < 16; ++i) s += xv[w][i];
        rs[w] = s * inv;   // (1+sum x)/den for epilogue
    }
    // normalized nfs (fp32) out
    float* on = out_nfs + (size_t)b * NR;
#pragma unroll
    for (int it = 0; it < 16; ++it) {
        int r0 = it * 256 + lane * 4;
        short4v v4 = *(const short4v*)&afrag[w][r0];
        floatx4 o;
#pragma unroll
        for (int e = 0; e < 4; ++e) o[e] = bf2f((u16)v4[e]) * inv;
        *(floatx4*)(on + r0) = o;
    }
    __syncthreads();

    // ---- gemm: wave w -> cols [16w, 16w+16), rows b0..b0+3 (M-rows 4..15 unused) ----
    int col = w * 16 + (lane & 15);
    int r = lane & 15;
    int ar = (r < 4) ? r : 0;                   // C rows 4..15 discarded; A garbage ok
    const u16* bptr = s_consT + (size_t)col * NR + (lane >> 4) * 8;
    const u16* aLds = &afrag[ar][(lane >> 4) * 8];
    floatx4 acc = {};
#pragma unroll 8
    for (int kt = 0; kt < NR / 32; ++kt) {
        short8 bf = *(const short8*)(bptr + kt * 32);
        short8 af = *(const short8*)(aLds + kt * 32);
        acc = __builtin_amdgcn_mfma_f32_16x16x32_bf16(af, bf, acc, 0, 0, 0);
    }
    if (lane < 16) {   // holds C rows 0..3 for its col
#pragma unroll
        for (int reg = 0; reg < 4; ++reg)
            out_rule[(size_t)(b0 + reg) * NC + col] = acc[reg] * rs[reg];
    }
}

extern "C" void kernel_launch(void* const* d_in, const int* in_sizes, int n_in,
                              void* d_out, int out_size, void* d_ws, size_t ws_size,
                              hipStream_t stream) {
    const float* x = (const float*)d_in[0];
    const float* centers = (const float*)d_in[1];
    const float* widths = (const float*)d_in[2];
    const float* cons = (const float*)d_in[3];
    const int* rules = (const int*)d_in[4];

    float* out = (float*)d_out;
    float* out_rule = out;                        // [1024,64]
    float* out_nfs = out + NB * NC;               // [1024,4096]
    float* out_xe = out + NB * NC + NB * NR;      // [1024,17]

    char* ws = (char*)d_ws;
    u16* s_consT = (u16*)ws;                      // 512 KB
    u32* packed = (u32*)(ws + (512 << 10));       // 16 KB

    k_prep<<<272, 256, 0, stream>>>(cons, rules, s_consT, packed);
    k_fused<<<NB / 4, 256, 0, stream>>>(x, centers, widths, packed, s_consT,
                                        out_nfs, out_xe, out_rule);
}